// Round 15
// baseline (1611.828 us; speedup 1.0000x reference)
//
#include <hip/hip_runtime.h>
#include <cstddef>

#define T_ 1024
#define B_ 128
#define F_ 243
#define H_ 20
#define G_ 60   // 3*H
#define R_ 512  // B*POOL
#define P_ 8    // steps per group
#define NG_ (T_ / P_)   // 128 groups
#define FP_ 256 // padded F for Wt (f-major transposed W_ih)
#define HS_ 244 // h_seq row stride: 976 B -> 16-B aligned rows

__device__ __forceinline__ float rdlane(float v, int l) {
  return __int_as_float(__builtin_amdgcn_readlane(__float_as_int(v), l));
}
#define RCP(x) __builtin_amdgcn_rcpf(x)
#if __has_builtin(__builtin_amdgcn_exp2f)
#define EXP2(x) __builtin_amdgcn_exp2f(x)
#else
#define EXP2(x) __expf((x) * 0.6931471805599453f)
#endif
#define NL2E_ -1.4426950408889634f   // -log2(e)
#define L2E2_ 2.8853900817779268f    // 2*log2(e)

// ---------------- K1a: streaming max-pool(4): feats -> h_seq (b-major, stride 244) -------
// Unchanged from r14 (validated r7-r14). Blocks 0..59 also build Wt[256][60]
// (f-major transpose of W_ih, rows f>=243 ZERO -- k2 relies on row 243 = 0 to
// null h_seq's garbage pad column); k2 launches after k1a.
__global__ __launch_bounds__(256) void k1a_pool(
    const float* __restrict__ feats, float* __restrict__ h_seq,
    const float* __restrict__ W_ih, float* __restrict__ Wt)
{
  const int bid = blockIdx.x;           // 16384 = 1024 t x 16 b-groups
  if (bid < 60) {                       // folded transpose: 60*256 >= FP_*G_
    const int i = bid * 256 + threadIdx.x;
    if (i < FP_ * G_) {
      const int f = i / G_, g = i - f * G_;
      Wt[(size_t)f * G_ + g] = (f < F_) ? W_ih[(size_t)g * F_ + f] : 0.f;
    }
  }
  const int t = bid & (T_ - 1);
  const int b0 = (bid >> 10) << 3;      // 8 batch rows per block
  const int col = threadIdx.x;
  if (col < F_) {
    #pragma unroll
    for (int bb = 0; bb < 8; ++bb) {
      const float* p =
          feats + ((size_t)t * R_ + (size_t)(b0 + bb) * 4) * F_ + col;
      const float v =
          fmaxf(fmaxf(p[0], p[F_]), fmaxf(p[2 * F_], p[3 * F_]));
      h_seq[((size_t)(b0 + bb) * T_ + t) * HS_ + col] = v;
    }
  }
}

// ---------------- K2: mega-fused  x-gate GEMM + recurrence + decoder + loss --------------
// One block per batch row, 5 waves. Wave 0 = r14's validated register
// recurrence; per group it ds_reads its 24 pre-scaled x-gate values from
// xgbuf and publishes e into ebuf; one barrier per group. Waves 1-4, in
// interval m: (a) GEMM group m+1 (xg = h_seq @ W_ih^T + b_ih, scaled by the
// exp2 fold, W from LDS Ws, A float4s from global/L1) into xgbuf[(m+1)&1],
// (b) decode group m-1 from ebuf[(m-1)&1]. Frames are offset one barrier
// interval, so 2 buffers suffice: producer reads xgbuf[m&1] (written interval
// m-1), consumers write xgbuf[(m+1)&1] -- disjoint; ebuf likewise.
// Replaces the separate k1b kernel (its ~50 us hides under the recurrence).
__global__ __launch_bounds__(320) void k2_mega(
    const float* __restrict__ e0, const float* __restrict__ W_hh,
    const float* __restrict__ b_hh, const float* __restrict__ Wt,
    const float* __restrict__ b_ih, const float* __restrict__ h_seq,
    const float* __restrict__ W_dec, const float* __restrict__ b_dec,
    float* __restrict__ partials)
{
  __shared__ __align__(16) float Ws[244 * 60];   // 58,560 B (row 243 = zeros)
  __shared__ float xgbuf[2][P_][G_];             //  3,840 B
  __shared__ float ebuf[2][P_][H_];              //  1,280 B
  __shared__ float red[8];
  const int b = blockIdx.x;
  const int tid = threadIdx.x;
  const int lane = tid & 63;
  const int wave = tid >> 6;
  const float* hsb = h_seq + (size_t)b * T_ * HS_;
  float acc = 0.f;   // producer wave leaves 0

  // stage W_ih^T rows 0..243 into LDS (all waves)
  for (int i = tid; i < 244 * 60; i += 320) Ws[i] = Wt[i];
  __syncthreads();                               // bar A

  if (wave == 0) {
    // ---------------- producer: recurrence (r14 math, LDS-fed) ----------------
    const bool own = lane < H_;
    const int j0 = own ? lane : 0;

    float2 wr2[10], wz2[10], wn2[10];
    #pragma unroll
    for (int k = 0; k < 10; ++k) {
      const float2 a = *(const float2*)&W_hh[j0 * H_ + 2 * k];
      const float2 c = *(const float2*)&W_hh[(j0 + 20) * H_ + 2 * k];
      const float2 d = *(const float2*)&W_hh[(j0 + 40) * H_ + 2 * k];
      wr2[k] = make_float2(a.x * NL2E_, a.y * NL2E_);
      wz2[k] = make_float2(c.x * NL2E_, c.y * NL2E_);
      wn2[k] = make_float2(d.x * L2E2_, d.y * L2E2_);
    }
    const float bhr = b_hh[j0] * NL2E_;
    const float bhz = b_hh[j0 + 20] * NL2E_;
    const float bhn = b_hh[j0 + 40] * L2E2_;

    float e_own = e0[b * H_ + j0];
    float2 es2[10];
    #pragma unroll
    for (int k = 0; k < 10; ++k) {
      es2[k].x = rdlane(e_own, 2 * k);
      es2[k].y = rdlane(e_own, 2 * k + 1);
    }
    __syncthreads();                             // bar B (xgbuf[0] ready)

    float xr[P_], xz[P_], xn[P_];

#define STEP(j)                                                            \
    {                                                                      \
      const float xrv = xr[j], xzv = xz[j], xnv = xn[j];                   \
      float2 rA = make_float2(bhr, 0.f), rB = make_float2(0.f, 0.f);       \
      float2 zA = make_float2(bhz, 0.f), zB = make_float2(0.f, 0.f);       \
      float2 nA = make_float2(bhn, 0.f), nB = make_float2(0.f, 0.f);       \
      _Pragma("unroll")                                                    \
      for (int k = 0; k < 5; ++k) {                                        \
        rA = wr2[k] * es2[k] + rA;   rB = wr2[k + 5] * es2[k + 5] + rB;    \
        zA = wz2[k] * es2[k] + zA;   zB = wz2[k + 5] * es2[k + 5] + zB;    \
        nA = wn2[k] * es2[k] + nA;   nB = wn2[k + 5] * es2[k + 5] + nB;    \
      }                                                                    \
      const float hr2 = (rA.x + rB.x) + (rA.y + rB.y);                     \
      const float hz2 = (zA.x + zB.x) + (zA.y + zB.y);                     \
      const float hn2 = (nA.x + nB.x) + (nA.y + nB.y);                     \
      const float rg = RCP(1.f + EXP2(xrv + hr2));                         \
      const float zg = RCP(1.f + EXP2(xzv + hz2));                         \
      const float aa2 = fmaf(rg, hn2, xnv);                                \
      const float ng = fmaf(-2.f, RCP(EXP2(aa2) + 1.f), 1.f);              \
      const float enew = fmaf(zg, e_own - ng, ng);                         \
      if (own) ebuf[m & 1][j][lane] = enew;                                \
      e_own = enew;                                                        \
      _Pragma("unroll")                                                    \
      for (int k = 0; k < 10; ++k) {                                       \
        es2[k].x = rdlane(enew, 2 * k);                                    \
        es2[k].y = rdlane(enew, 2 * k + 1);                                \
      }                                                                    \
    }

    for (int m = 0; m < NG_; ++m) {
      const float* xb = &xgbuf[m & 1][0][0];
      #pragma unroll
      for (int j = 0; j < P_; ++j) {             // 24 ds_reads, latency hides
        xr[j] = xb[j * G_ + j0];                 // under step 0's dot
        xz[j] = xb[j * G_ + j0 + 20];
        xn[j] = xb[j * G_ + j0 + 40];
      }
      STEP(0) STEP(1) STEP(2) STEP(3) STEP(4) STEP(5) STEP(6) STEP(7)
      __syncthreads();                           // publish group m
    }
    __syncthreads();                             // pair consumers' last interval
#undef STEP
  } else {
    // ---------------- consumers: x-gate GEMM + decoder + loss ----------------
    const int ct = tid - 64;                     // 0..255
    const int rr = ct >> 5;                      // GEMM row 0..7
    const int q = ct & 31;                       // GEMM gate-pair 0..31
    const bool qact = q < 30;
    const bool act = ct < F_;
    const int f = act ? ct : 0;

    float wd[H_];
    #pragma unroll
    for (int k = 0; k < H_; ++k) wd[k] = W_dec[f * H_ + k];
    const float bd = b_dec[f];

    float2 sc2 = make_float2(0.f, 0.f), bs2 = make_float2(0.f, 0.f);
    if (qact) {
      const float s = (q < 20) ? NL2E_ : L2E2_;  // gates <40: sigmoid fold
      sc2 = make_float2(s, s);
      bs2 = make_float2(b_ih[2 * q] * s, b_ih[2 * q + 1] * s);
    }

#define GEMM_GRP(GRP, BUF)                                                 \
    if (qact) {                                                            \
      const float* hrow = hsb + (size_t)((GRP) * P_ + rr) * HS_;           \
      float2 aE = make_float2(0.f, 0.f), aO = make_float2(0.f, 0.f);       \
      _Pragma("unroll 4")                                                  \
      for (int f4 = 0; f4 < 61; ++f4) {                                    \
        const float4 h4 = *(const float4*)&hrow[f4 * 4];                   \
        const float2 u0 = *(const float2*)&Ws[(f4 * 4 + 0) * 60 + 2 * q];  \
        const float2 u1 = *(const float2*)&Ws[(f4 * 4 + 1) * 60 + 2 * q];  \
        const float2 u2 = *(const float2*)&Ws[(f4 * 4 + 2) * 60 + 2 * q];  \
        const float2 u3 = *(const float2*)&Ws[(f4 * 4 + 3) * 60 + 2 * q];  \
        aE = u0 * make_float2(h4.x, h4.x) + aE;                            \
        aO = u1 * make_float2(h4.y, h4.y) + aO;                            \
        aE = u2 * make_float2(h4.z, h4.z) + aE;                            \
        aO = u3 * make_float2(h4.w, h4.w) + aO;                            \
      }                                                                    \
      const float2 a2 = (aE + aO) * sc2 + bs2;                             \
      *(float2*)&xgbuf[BUF][rr][2 * q] = a2;                               \
    }

    GEMM_GRP(0, 0)                               // prologue: group 0
    float hcur[P_], hnxt[P_];
    #pragma unroll
    for (int j = 0; j < P_; ++j) hcur[j] = hsb[(size_t)j * HS_ + f];
    __syncthreads();                             // bar B

    for (int m = 0; m <= NG_; ++m) {
      if (m >= 1 && m < NG_) {                   // h rows for NEXT decode
        #pragma unroll
        for (int j = 0; j < P_; ++j)
          hnxt[j] = hsb[(size_t)(P_ * m + j) * HS_ + f];
      }
      if (m <= NG_ - 2) GEMM_GRP(m + 1, (m + 1) & 1)
      if (m >= 1) {                              // decode group m-1
        const float* eb = &ebuf[(m - 1) & 1][0][0];
        #pragma unroll
        for (int j = 0; j < P_; ++j) {
          const float2* ep = (const float2*)&eb[j * H_];
          float d = bd;
          #pragma unroll
          for (int k = 0; k < 10; ++k) {
            const float2 e2 = ep[k];
            d = fmaf(wd[2 * k], e2.x, fmaf(wd[2 * k + 1], e2.y, d));
          }
          const float fo = fmaxf(d, 0.f);
          const float df = fo - hcur[j];
          if (act) acc = fmaf(df, df, acc);
        }
        #pragma unroll
        for (int j = 0; j < P_; ++j) hcur[j] = hnxt[j];
      }
      __syncthreads();
    }
#undef GEMM_GRP
  }

  // deterministic block reduction (producer contributes 0)
  #pragma unroll
  for (int m = 32; m >= 1; m >>= 1) acc += __shfl_xor(acc, m);
  if (lane == 0) red[wave] = acc;
  __syncthreads();
  if (tid == 0)
    partials[b] = ((red[0] + red[1]) + (red[2] + red[3])) + red[4];
}

// ---------------- K3: final deterministic reduction over 128 partials ----------------
__global__ __launch_bounds__(64) void k3_reduce(
    const float* __restrict__ partials, float* __restrict__ out)
{
  const int lane = threadIdx.x;
  float a = partials[lane] + partials[lane + 64];
  #pragma unroll
  for (int m = 32; m >= 1; m >>= 1) a += __shfl_xor(a, m);
  if (lane == 0) out[0] = a * (float)(1.0 / ((double)T_ * B_ * F_));
}

extern "C" void kernel_launch(void* const* d_in, const int* in_sizes, int n_in,
                              void* d_out, int out_size, void* d_ws, size_t ws_size,
                              hipStream_t stream) {
  const float* feats = (const float*)d_in[0];
  const float* e0    = (const float*)d_in[1];
  const float* W_ih  = (const float*)d_in[2];
  const float* W_hh  = (const float*)d_in[3];
  const float* b_ih  = (const float*)d_in[4];
  const float* b_hh  = (const float*)d_in[5];
  const float* W_dec = (const float*)d_in[6];
  const float* b_dec = (const float*)d_in[7];
  float* out = (float*)d_out;

  float* ws = (float*)d_ws;
  float* h_seq    = ws;                                    // B*T*HS_ floats (b-major, padded)
  float* Wt       = ws + (size_t)B_ * T_ * HS_;            // FP_*G_ floats
  float* partials = Wt + (size_t)FP_ * G_;                 // 128 floats

  hipLaunchKernelGGL(k1a_pool, dim3(T_ * (B_ / 8)), dim3(256), 0, stream,
                     feats, h_seq, W_ih, Wt);
  hipLaunchKernelGGL(k2_mega, dim3(B_), dim3(320), 0, stream,
                     e0, W_hh, b_hh, Wt, b_ih, h_seq, W_dec, b_dec, partials);
  hipLaunchKernelGGL(k3_reduce, dim3(1), dim3(64), 0, stream,
                     partials, out);
}

// Round 16
// 444.186 us; speedup vs baseline: 3.6287x; 3.6287x over previous
//
#include <hip/hip_runtime.h>
#include <cstddef>

#define T_ 1024
#define B_ 128
#define F_ 243
#define H_ 20
#define G_ 60   // 3*H
#define R_ 512  // B*POOL
#define P_ 8    // xg prefetch depth / e-group size in k2
#define FP_ 256 // padded F for Wt (f-major transposed W_ih)
#define HS_ 244 // h_seq row stride: 244 floats = 976 B -> 16-B aligned rows

__device__ __forceinline__ float rdlane(float v, int l) {
  return __int_as_float(__builtin_amdgcn_readlane(__float_as_int(v), l));
}
#define RCP(x) __builtin_amdgcn_rcpf(x)
#if __has_builtin(__builtin_amdgcn_exp2f)
#define EXP2(x) __builtin_amdgcn_exp2f(x)
#else
#define EXP2(x) __expf((x) * 0.6931471805599453f)
#endif
#define NL2E_ -1.4426950408889634f   // -log2(e)
#define L2E2_ 2.8853900817779268f    // 2*log2(e)

// ---------------- K1a: streaming max-pool(4): feats -> h_seq (b-major, stride 244) -------
// Fully contiguous 972-B reads/writes, no LDS, no barriers (validated r7-r14).
// Blocks 0..59 additionally build Wt[256][60] (f-major transpose of W_ih,
// rows f>=243 zero); k1b launches after k1a so Wt is complete when consumed.
__global__ __launch_bounds__(256) void k1a_pool(
    const float* __restrict__ feats, float* __restrict__ h_seq,
    const float* __restrict__ W_ih, float* __restrict__ Wt)
{
  const int bid = blockIdx.x;           // 16384 = 1024 t x 16 b-groups
  if (bid < 60) {                       // folded k0: 60*256 >= FP_*G_
    const int i = bid * 256 + threadIdx.x;
    if (i < FP_ * G_) {
      const int f = i / G_, g = i - f * G_;
      Wt[(size_t)f * G_ + g] = (f < F_) ? W_ih[(size_t)g * F_ + f] : 0.f;
    }
  }
  const int t = bid & (T_ - 1);
  const int b0 = (bid >> 10) << 3;      // 8 batch rows per block
  const int col = threadIdx.x;
  if (col < F_) {
    #pragma unroll
    for (int bb = 0; bb < 8; ++bb) {
      const float* p =
          feats + ((size_t)t * R_ + (size_t)(b0 + bb) * 4) * F_ + col;
      const float v =
          fmaxf(fmaxf(p[0], p[F_]), fmaxf(p[2 * F_], p[3 * F_]));
      h_seq[((size_t)(b0 + bb) * T_ + t) * HS_ + col] = v;
    }
  }
}

// ---------------- K1b: GEMM  xg = h_seq @ W_ih^T + b_ih  (r11/r13 version, validated) ----
// A read directly from global (16 lanes of a rg-group load the SAME float4;
// coalescer collapses, L1-resident), consumed immediately -> no spills. Only
// Ws (15 KB/chunk) in LDS. 64-row blocks (grid 2048) so one block's Ws-stage
// barriers hide under other blocks' FMA phases. Output: [b][t][G] float4s.
// NOTE (r15 lesson): these A loads are hidden by multi-block TLP; moving this
// GEMM onto k2's barrier-locked critical path serializes the latency (3x).
__global__ __launch_bounds__(256) void k1b_gemm(
    const float* __restrict__ h_seq, const float* __restrict__ Wt,
    const float* __restrict__ b_ih, float* __restrict__ xg)
{
  __shared__ __align__(16) float Ws[64 * 60];    // 15 KB, f-major chunk
  const int bid = blockIdx.x;
  const int b = bid >> 4;
  const int t0 = (bid & 15) << 6;          // 16 t-chunks of 64 rows
  const int tid = threadIdx.x;
  const int rg = tid >> 4;                 // 0..15 -> rows rg*4..rg*4+3
  const int gcol = tid & 15;               // 0..15 -> gates gcol*4..+3
  const int gc4 = (gcol < 15) ? gcol * 4 : 56;   // clamp col 15 (dup of 14)
  const float* hsb = h_seq + ((size_t)b * T_ + t0) * HS_;

  float acc[4][4];
  #pragma unroll
  for (int i = 0; i < 4; ++i)
    #pragma unroll
    for (int j = 0; j < 4; ++j) acc[i][j] = 0.f;

  for (int c = 0; c < 4; ++c) {            // f-chunks of 64
    const int FC = c * 64;
    __syncthreads();                       // Ws readers of chunk c-1 done
    for (int j = tid; j < 64 * 60; j += 256)
      Ws[j] = Wt[(size_t)FC * G_ + j];
    __syncthreads();
    #pragma unroll
    for (int fj = 0; fj < 16; ++fj) {
      const float* wp = &Ws[(fj * 4) * 60 + gc4];
      const float4 w0 = *(const float4*)(wp);
      const float4 w1 = *(const float4*)(wp + 60);
      const float4 w2 = *(const float4*)(wp + 120);
      const float4 w3 = *(const float4*)(wp + 180);
      #pragma unroll
      for (int i = 0; i < 4; ++i) {
        const int row = (rg << 2) + i;
        const float4 a4 =
            *(const float4*)&hsb[(size_t)row * HS_ + FC + fj * 4];
        acc[i][0] = fmaf(a4.x, w0.x, fmaf(a4.y, w1.x, fmaf(a4.z, w2.x, fmaf(a4.w, w3.x, acc[i][0]))));
        acc[i][1] = fmaf(a4.x, w0.y, fmaf(a4.y, w1.y, fmaf(a4.z, w2.y, fmaf(a4.w, w3.y, acc[i][1]))));
        acc[i][2] = fmaf(a4.x, w0.z, fmaf(a4.y, w1.z, fmaf(a4.z, w2.z, fmaf(a4.w, w3.z, acc[i][2]))));
        acc[i][3] = fmaf(a4.x, w0.w, fmaf(a4.y, w1.w, fmaf(a4.z, w2.w, fmaf(a4.w, w3.w, acc[i][3]))));
      }
    }
  }

  if (gcol < 15) {
    const float4 bi4 = *(const float4*)&b_ih[gc4];
    #pragma unroll
    for (int i = 0; i < 4; ++i) {
      const int row = (rg << 2) + i;
      float4 o;
      o.x = acc[i][0] + bi4.x;  o.y = acc[i][1] + bi4.y;
      o.z = acc[i][2] + bi4.z;  o.w = acc[i][3] + bi4.w;
      *(float4*)&xg[((size_t)b * T_ + t0 + row) * G_ + gc4] = o;
    }
  }
}

// ---------------- K2: fused recurrence + decoder + loss (r14, validated 445 us) ----------
// 5 waves per block, one block per batch row. Wave 0 = register recurrence
// (lane j<20 owns gate triple; e broadcast via readlane; 3 dword xg loads per
// step with depth-8 rotating prefetch; exp2 constants folded into weights at
// load). Publishes e(t) into ping-pong LDS ebuf; one barrier per 8 steps.
// Waves 1-4 decode group g while the producer computes g+1.
__global__ __launch_bounds__(320) void k2_fused(
    const float* __restrict__ e0, const float* __restrict__ W_hh,
    const float* __restrict__ b_hh, const float* __restrict__ xg,
    const float* __restrict__ h_seq, const float* __restrict__ W_dec,
    const float* __restrict__ b_dec, float* __restrict__ partials)
{
  __shared__ float ebuf[2][P_][H_];   // 1280 B ping-pong
  __shared__ float red[8];
  const int b = blockIdx.x;
  const int tid = threadIdx.x;
  const int lane = tid & 63;
  const int wave = tid >> 6;
  float acc = 0.f;   // producer wave leaves 0

  if (wave == 0) {
    // ---------------- producer: recurrence ----------------
    const bool own = lane < H_;
    const int j0 = own ? lane : 0;

    float2 wr2[10], wz2[10], wn2[10];
    #pragma unroll
    for (int k = 0; k < 10; ++k) {
      const float2 a = *(const float2*)&W_hh[j0 * H_ + 2 * k];
      const float2 c = *(const float2*)&W_hh[(j0 + 20) * H_ + 2 * k];
      const float2 d = *(const float2*)&W_hh[(j0 + 40) * H_ + 2 * k];
      wr2[k] = make_float2(a.x * NL2E_, a.y * NL2E_);
      wz2[k] = make_float2(c.x * NL2E_, c.y * NL2E_);
      wn2[k] = make_float2(d.x * L2E2_, d.y * L2E2_);
    }
    const float bhr = b_hh[j0] * NL2E_;
    const float bhz = b_hh[j0 + 20] * NL2E_;
    const float bhn = b_hh[j0 + 40] * L2E2_;

    float e_own = e0[b * H_ + j0];
    float2 es2[10];
    #pragma unroll
    for (int k = 0; k < 10; ++k) {
      es2[k].x = rdlane(e_own, 2 * k);
      es2[k].y = rdlane(e_own, 2 * k + 1);
    }

    const float* xgb = xg + (size_t)b * T_ * G_;
    float xr[P_], xz[P_], xn[P_];
    #pragma unroll
    for (int j = 0; j < P_; ++j) {
      xr[j] = xgb[(size_t)j * G_ + j0] * NL2E_;
      xz[j] = xgb[(size_t)j * G_ + j0 + 20] * NL2E_;
      xn[j] = xgb[(size_t)j * G_ + j0 + 40] * L2E2_;
    }

#define STEP(j, RELOAD)                                                    \
    {                                                                      \
      const int t = t0 + (j);                                              \
      const float xrv = xr[j], xzv = xz[j], xnv = xn[j];                   \
      if (RELOAD) {                                                        \
        const float* xp = xgb + (size_t)(t + P_) * G_;                     \
        xr[j] = xp[j0] * NL2E_;                                            \
        xz[j] = xp[j0 + 20] * NL2E_;                                       \
        xn[j] = xp[j0 + 40] * L2E2_;                                       \
      }                                                                    \
      float2 rA = make_float2(bhr, 0.f), rB = make_float2(0.f, 0.f);       \
      float2 zA = make_float2(bhz, 0.f), zB = make_float2(0.f, 0.f);       \
      float2 nA = make_float2(bhn, 0.f), nB = make_float2(0.f, 0.f);       \
      _Pragma("unroll")                                                    \
      for (int k = 0; k < 5; ++k) {                                        \
        rA = wr2[k] * es2[k] + rA;   rB = wr2[k + 5] * es2[k + 5] + rB;    \
        zA = wz2[k] * es2[k] + zA;   zB = wz2[k + 5] * es2[k + 5] + zB;    \
        nA = wn2[k] * es2[k] + nA;   nB = wn2[k + 5] * es2[k + 5] + nB;    \
      }                                                                    \
      const float hr2 = (rA.x + rB.x) + (rA.y + rB.y);                     \
      const float hz2 = (zA.x + zB.x) + (zA.y + zB.y);                     \
      const float hn2 = (nA.x + nB.x) + (nA.y + nB.y);                     \
      const float rg = RCP(1.f + EXP2(xrv + hr2));                         \
      const float zg = RCP(1.f + EXP2(xzv + hz2));                         \
      const float aa2 = fmaf(rg, hn2, xnv);                                \
      const float ng = fmaf(-2.f, RCP(EXP2(aa2) + 1.f), 1.f);              \
      const float enew = fmaf(zg, e_own - ng, ng);                         \
      if (own) ebuf[(t0 >> 3) & 1][j][lane] = enew;                        \
      e_own = enew;                                                        \
      _Pragma("unroll")                                                    \
      for (int k = 0; k < 10; ++k) {                                       \
        es2[k].x = rdlane(enew, 2 * k);                                    \
        es2[k].y = rdlane(enew, 2 * k + 1);                                \
      }                                                                    \
    }

    for (int t0 = 0; t0 < T_ - P_; t0 += P_) {
      STEP(0, true) STEP(1, true) STEP(2, true) STEP(3, true)
      STEP(4, true) STEP(5, true) STEP(6, true) STEP(7, true)
      __syncthreads();                 // publish group t0/8
    }
    {
      const int t0 = T_ - P_;
      STEP(0, false) STEP(1, false) STEP(2, false) STEP(3, false)
      STEP(4, false) STEP(5, false) STEP(6, false) STEP(7, false)
      __syncthreads();                 // publish last group
    }
#undef STEP
  } else {
    // ---------------- consumers: decoder + squared error ----------------
    const int ct = tid - 64;           // 0..255
    const bool act = ct < F_;
    const int f = act ? ct : 0;
    float wd[H_];
    #pragma unroll
    for (int k = 0; k < H_; ++k) wd[k] = W_dec[f * H_ + k];
    const float bd = b_dec[f];
    const float* hsb = h_seq + (size_t)b * T_ * HS_;

    float hcur[P_], hnxt[P_];
    #pragma unroll
    for (int j = 0; j < P_; ++j) hcur[j] = hsb[(size_t)j * HS_ + f];

    for (int g = 0; g < T_ / P_; ++g) {
      __syncthreads();                 // ebuf group g published
      if (g < T_ / P_ - 1) {
        #pragma unroll
        for (int j = 0; j < P_; ++j)
          hnxt[j] = hsb[(size_t)(P_ * (g + 1) + j) * HS_ + f];
      }
      const float* eb = &ebuf[g & 1][0][0];
      #pragma unroll
      for (int j = 0; j < P_; ++j) {
        const float2* ep = (const float2*)&eb[j * H_];
        float d = bd;
        #pragma unroll
        for (int k = 0; k < 10; ++k) {
          const float2 e2 = ep[k];
          d = fmaf(wd[2 * k], e2.x, fmaf(wd[2 * k + 1], e2.y, d));
        }
        const float fo = fmaxf(d, 0.f);
        const float df = fo - hcur[j];
        if (act) acc = fmaf(df, df, acc);
      }
      #pragma unroll
      for (int j = 0; j < P_; ++j) hcur[j] = hnxt[j];
    }
  }

  // deterministic block reduction (producer contributes 0)
  #pragma unroll
  for (int m = 32; m >= 1; m >>= 1) acc += __shfl_xor(acc, m);
  if (lane == 0) red[wave] = acc;
  __syncthreads();
  if (tid == 0)
    partials[b] = ((red[0] + red[1]) + (red[2] + red[3])) + red[4];
}

// ---------------- K3: final deterministic reduction over 128 partials ----------------
__global__ __launch_bounds__(64) void k3_reduce(
    const float* __restrict__ partials, float* __restrict__ out)
{
  const int lane = threadIdx.x;
  float a = partials[lane] + partials[lane + 64];
  #pragma unroll
  for (int m = 32; m >= 1; m >>= 1) a += __shfl_xor(a, m);
  if (lane == 0) out[0] = a * (float)(1.0 / ((double)T_ * B_ * F_));
}

extern "C" void kernel_launch(void* const* d_in, const int* in_sizes, int n_in,
                              void* d_out, int out_size, void* d_ws, size_t ws_size,
                              hipStream_t stream) {
  const float* feats = (const float*)d_in[0];
  const float* e0    = (const float*)d_in[1];
  const float* W_ih  = (const float*)d_in[2];
  const float* W_hh  = (const float*)d_in[3];
  const float* b_ih  = (const float*)d_in[4];
  const float* b_hh  = (const float*)d_in[5];
  const float* W_dec = (const float*)d_in[6];
  const float* b_dec = (const float*)d_in[7];
  float* out = (float*)d_out;

  float* ws = (float*)d_ws;
  float* h_seq    = ws;                                    // B*T*HS_ floats (b-major, padded)
  float* xgates   = ws + (size_t)B_ * T_ * HS_;            // B*T*G floats (b-major)
  float* partials = xgates + (size_t)B_ * T_ * G_;         // 128 floats
  float* Wt       = partials + 128;                        // FP_*G_ floats

  hipLaunchKernelGGL(k1a_pool, dim3(T_ * (B_ / 8)), dim3(256), 0, stream,
                     feats, h_seq, W_ih, Wt);
  hipLaunchKernelGGL(k1b_gemm, dim3(B_ * 16), dim3(256), 0, stream,
                     h_seq, Wt, b_ih, xgates);
  hipLaunchKernelGGL(k2_fused, dim3(B_), dim3(320), 0, stream,
                     e0, W_hh, b_hh, xgates, h_seq, W_dec, b_dec, partials);
  hipLaunchKernelGGL(k3_reduce, dim3(1), dim3(64), 0, stream,
                     partials, out);
}